// Round 10
// baseline (1292.667 us; speedup 1.0000x reference)
//
#include <hip/hip_runtime.h>

typedef unsigned short u16;
typedef unsigned int u32;
typedef __bf16 bf16x8 __attribute__((ext_vector_type(8)));
typedef u16 u16x8 __attribute__((ext_vector_type(8)));
typedef float f32x4 __attribute__((ext_vector_type(4)));

#define KOFF 27
#define KPAD 28
#define EPSV 1e-5f
#define FRAGS_PER_CONV 14336  // 28 k-slots * 512 fragments (u16x8 units)
#define LDS_S 133             // LDS row stride (ints) for prep_tcidx

__device__ __forceinline__ u16 f2bf(float f) {
  u32 u = __builtin_bit_cast(u32, f);
  u = (u + 0x7FFFu + ((u >> 16) & 1u)) >> 16;
  return (u16)u;
}
__device__ __forceinline__ float bf2f(u16 h) {
  return __builtin_bit_cast(float, (u32)h << 16);
}

// async gather: per-lane global src, LDS dest = uniform base + lane*16, no VGPR dest
__device__ __forceinline__ void gl_lds16(const void* g, void* l) {
  __builtin_amdgcn_global_load_lds(
      (__attribute__((address_space(1))) void*)g,
      (__attribute__((address_space(3))) void*)l, 16, 0, 0);
}

// ---- x (f32) -> bf16, vectorized; zero sentinel row at index N ----
__global__ void prep_x(const float* __restrict__ x, u16* __restrict__ xg, int n8) {
  int tid = blockIdx.x * blockDim.x + threadIdx.x;
  int stride = gridDim.x * blockDim.x;
  for (int i = tid; i < n8; i += stride) {
    const f32x4* p = reinterpret_cast<const f32x4*>(x) + i * 2;
    f32x4 v0 = p[0], v1 = p[1];
    u16x8 o;
    o[0] = f2bf(v0[0]); o[1] = f2bf(v0[1]); o[2] = f2bf(v0[2]); o[3] = f2bf(v0[3]);
    o[4] = f2bf(v1[0]); o[5] = f2bf(v1[1]); o[6] = f2bf(v1[2]); o[7] = f2bf(v1[3]);
    reinterpret_cast<u16x8*>(xg)[i] = o;
  }
  if (tid < 8) {  // zero row N (sentinel target for masked gathers)
    u16x8 z;
#pragma unroll
    for (int j = 0; j < 8; j++) z[j] = 0;
    reinterpret_cast<u16x8*>(xg)[n8 + tid] = z;
  }
}

// ---- nbr+mask -> tile-major cidx_t[tile][28][16]; sentinel = N; k=27 pad ----
__global__ __launch_bounds__(256) void prep_tcidx(
    const int* __restrict__ nbr, const int* __restrict__ msk,
    int* __restrict__ cidx_t, int N) {
  __shared__ int lds[27 * LDS_S + 16];
  const int tid = threadIdx.x;
  const int blk = blockIdx.x;
  const int in_base = blk * (128 * KOFF);
#pragma unroll
  for (int it = 0; it < 14; it++) {
    int t = tid + it * 256;
    if (t < 128 * KOFF) {
      int g = in_base + t;
      int v = msk[g] ? nbr[g] : N;
      int row = (u32)t / KOFF;
      int k = t - row * KOFF;
      lds[k * LDS_S + row] = v;
    }
  }
  __syncthreads();
  const int out_base = blk * (8 * KPAD * 16);
#pragma unroll
  for (int it = 0; it < 14; it++) {
    int o = tid + it * 256;
    int tl = (u32)o / (KPAD * 16);
    int rem = o - tl * (KPAD * 16);
    int k = rem >> 4;
    int r = rem & 15;
    int v = (k < KOFF) ? lds[k * LDS_S + tl * 16 + r] : N;
    cidx_t[out_base + o] = v;
  }
}

// ---- W1,W2 -> bf16 B-fragments in MFMA lane order; k-slot 27 zeroed ----
__global__ void prep_w(const float* __restrict__ W1, const float* __restrict__ W2,
                       u16* __restrict__ wf) {
  int tid = blockIdx.x * blockDim.x + threadIdx.x;
  if (tid >= 2 * FRAGS_PER_CONV) return;
  int conv = tid / FRAGS_PER_CONV;
  int slot = tid - conv * FRAGS_PER_CONV;
  int k = slot >> 9;
  u16x8 o;
  if (k >= KOFF) {
#pragma unroll
    for (int j = 0; j < 8; j++) o[j] = 0;
  } else {
    const float* src = conv ? W2 : W1;
    int rest = slot & 511;
    int c = rest >> 8;
    int nt = (rest >> 6) & 3;
    int lane = rest & 63;
    int col = nt * 16 + (lane & 15);
    int kk0 = c * 32 + (lane >> 4) * 8;
    int base = k * 4096 + kk0 * 64 + col;
#pragma unroll
    for (int j = 0; j < 8; j++) o[j] = f2bf(src[base + j * 64]);
  }
  reinterpret_cast<u16x8*>(wf)[tid] = o;
}

// ---- sparse conv: 2 tiles/wave; A gathers -> ring-4 LDS via global_load_lds
// (depth-3), B double-buffered in registers (depth-1), single counted
// s_waitcnt vmcnt(6) per k-step; 28 uniform k-slots (slot 27 = zero pad) ----
__global__ __launch_bounds__(128) void sconv(
    const u16* __restrict__ xg, const int* __restrict__ cidx_t,
    const u16* __restrict__ wf, u16* __restrict__ hout,
    float* __restrict__ psum, float* __restrict__ psq) {
  __shared__ __align__(1024) char smem[32768];  // 2 waves * 4 bufs * 4KB
  const int lane = threadIdx.x & 63;
  const int r = lane & 15;        // A row within tile / C col within 16-group
  const int kg = lane >> 4;       // channel-group
  const int widInBlk = threadIdx.x >> 6;
  const int waveId = blockIdx.x * 2 + widInBlk;
  const bf16x8* wfv = reinterpret_cast<const bf16x8*>(wf);
  char* wbase = smem + widInBlk * 16384;
  const char* xgc = (const char*)xg;

  const int n0 = waveId * 32;
  const int* cpA = cidx_t + (size_t)(waveId * 2) * (KPAD * 16) + r;
  const int* cpB = cpA + KPAD * 16;

  f32x4 acc[2][4];
#pragma unroll
  for (int j = 0; j < 2; j++)
#pragma unroll
    for (int nt = 0; nt < 4; nt++) {
      acc[j][nt][0] = 0.f; acc[j][nt][1] = 0.f;
      acc[j][nt][2] = 0.f; acc[j][nt][3] = 0.f;
    }

#define SB0 __builtin_amdgcn_sched_barrier(0)

// 4 async gathers for one k-step into buffer bc: [tile][half] layout
#define STAGE(bc, idA, idB)                                          \
  {                                                                  \
    char* sb = wbase + (bc)*4096;                                    \
    const char* ga = xgc + ((size_t)(idA) << 7) + kg * 16;           \
    const char* gb = xgc + ((size_t)(idB) << 7) + kg * 16;           \
    gl_lds16(ga, sb);                                                \
    gl_lds16(ga + 64, sb + 1024);                                    \
    gl_lds16(gb, sb + 2048);                                         \
    gl_lds16(gb + 64, sb + 3072);                                    \
  }

#define MFMAS(C0, C1, C2, C3, C4, C5, C6, C7)                                          \
  acc[0][0] = __builtin_amdgcn_mfma_f32_16x16x32_bf16(a00, C0, acc[0][0], 0, 0, 0);    \
  acc[1][0] = __builtin_amdgcn_mfma_f32_16x16x32_bf16(a10, C0, acc[1][0], 0, 0, 0);    \
  acc[0][1] = __builtin_amdgcn_mfma_f32_16x16x32_bf16(a00, C1, acc[0][1], 0, 0, 0);    \
  acc[1][1] = __builtin_amdgcn_mfma_f32_16x16x32_bf16(a10, C1, acc[1][1], 0, 0, 0);    \
  acc[0][2] = __builtin_amdgcn_mfma_f32_16x16x32_bf16(a00, C2, acc[0][2], 0, 0, 0);    \
  acc[1][2] = __builtin_amdgcn_mfma_f32_16x16x32_bf16(a10, C2, acc[1][2], 0, 0, 0);    \
  acc[0][3] = __builtin_amdgcn_mfma_f32_16x16x32_bf16(a00, C3, acc[0][3], 0, 0, 0);    \
  acc[1][3] = __builtin_amdgcn_mfma_f32_16x16x32_bf16(a10, C3, acc[1][3], 0, 0, 0);    \
  acc[0][0] = __builtin_amdgcn_mfma_f32_16x16x32_bf16(a01, C4, acc[0][0], 0, 0, 0);    \
  acc[1][0] = __builtin_amdgcn_mfma_f32_16x16x32_bf16(a11, C4, acc[1][0], 0, 0, 0);    \
  acc[0][1] = __builtin_amdgcn_mfma_f32_16x16x32_bf16(a01, C5, acc[0][1], 0, 0, 0);    \
  acc[1][1] = __builtin_amdgcn_mfma_f32_16x16x32_bf16(a11, C5, acc[1][1], 0, 0, 0);    \
  acc[0][2] = __builtin_amdgcn_mfma_f32_16x16x32_bf16(a01, C6, acc[0][2], 0, 0, 0);    \
  acc[1][2] = __builtin_amdgcn_mfma_f32_16x16x32_bf16(a11, C6, acc[1][2], 0, 0, 0);    \
  acc[0][3] = __builtin_amdgcn_mfma_f32_16x16x32_bf16(a01, C7, acc[0][3], 0, 0, 0);    \
  acc[1][3] = __builtin_amdgcn_mfma_f32_16x16x32_bf16(a11, C7, acc[1][3], 0, 0, 0);

// one k-step: wait(6) -> ds_read A[k] -> prefetch B[k+1] -> stage A[k+3] ->
// idx[k+4] -> 16 MFMAs with B[k] (consume set CB*, prefetch set PB*)
#define HALF(KK, CB0, CB1, CB2, CB3, CB4, CB5, CB6, CB7,                          \
             PB0, PB1, PB2, PB3, PB4, PB5, PB6, PB7)                              \
  {                                                                               \
    asm volatile("s_waitcnt vmcnt(6)" ::: "memory");                              \
    SB0;                                                                          \
    const char* rb_ = wbase + ((KK)&3) * 4096;                                    \
    bf16x8 a00 = *(const bf16x8*)(rb_ + lane * 16);                               \
    bf16x8 a01 = *(const bf16x8*)(rb_ + 1024 + lane * 16);                        \
    bf16x8 a10 = *(const bf16x8*)(rb_ + 2048 + lane * 16);                        \
    bf16x8 a11 = *(const bf16x8*)(rb_ + 3072 + lane * 16);                        \
    SB0;                                                                          \
    int kb_ = (KK) + 1; kb_ = kb_ > 27 ? 27 : kb_;                                \
    const bf16x8* bpn_ = wfv + (kb_ << 9) + lane;                                 \
    PB0 = bpn_[0];   PB1 = bpn_[64];  PB2 = bpn_[128]; PB3 = bpn_[192];           \
    PB4 = bpn_[256]; PB5 = bpn_[320]; PB6 = bpn_[384]; PB7 = bpn_[448];           \
    SB0;                                                                          \
    STAGE(((KK) + 3) & 3, nidA, nidB);                                            \
    SB0;                                                                          \
    int j_ = (KK) + 4; j_ = j_ > 27 ? 27 : j_;                                    \
    nidA = cpA[j_ << 4]; nidB = cpB[j_ << 4];                                     \
    SB0;                                                                          \
    MFMAS(CB0, CB1, CB2, CB3, CB4, CB5, CB6, CB7)                                 \
  }

  bf16x8 be0, be1, be2, be3, be4, be5, be6, be7;
  bf16x8 bo0, bo1, bo2, bo3, bo4, bo5, bo6, bo7;

  // prologue: ids 0..2, stage k=0,1, B_0 loads, stage k=2, ids for k=3
  // (vm order tail = [B_0:8][S_2:4][I_3:2] -> first wait vmcnt(6) retires B_0,S_0)
  int iA0 = cpA[0], iB0 = cpB[0];
  int iA1 = cpA[16], iB1 = cpB[16];
  int iA2 = cpA[32], iB2 = cpB[32];
  SB0;
  STAGE(0, iA0, iB0);
  SB0;
  STAGE(1, iA1, iB1);
  SB0;
  {
    const bf16x8* bp0 = wfv + lane;
    be0 = bp0[0];   be1 = bp0[64];  be2 = bp0[128]; be3 = bp0[192];
    be4 = bp0[256]; be5 = bp0[320]; be6 = bp0[384]; be7 = bp0[448];
  }
  SB0;
  STAGE(2, iA2, iB2);
  SB0;
  int nidA = cpA[48], nidB = cpB[48];
  SB0;

#pragma unroll 1
  for (int t = 0; t < 14; t++) {
    const int k0 = 2 * t;
    HALF(k0, be0, be1, be2, be3, be4, be5, be6, be7,
         bo0, bo1, bo2, bo3, bo4, bo5, bo6, bo7);
    HALF(k0 + 1, bo0, bo1, bo2, bo3, bo4, bo5, bo6, bo7,
         be0, be1, be2, be3, be4, be5, be6, be7);
  }
#undef HALF
#undef MFMAS
#undef STAGE
#undef SB0

  // C/D layout: col = lane&15 (+16*nt), row = kg*4 + reg (+16*tile)
  float ssum[4] = {0.f, 0.f, 0.f, 0.f};
  float ssq[4] = {0.f, 0.f, 0.f, 0.f};
#pragma unroll
  for (int j = 0; j < 2; j++) {
#pragma unroll
    for (int nt = 0; nt < 4; nt++) {
      const int col = nt * 16 + r;
      float rs = 0.f, rq = 0.f;
#pragma unroll
      for (int reg = 0; reg < 4; reg++) {
        float v = acc[j][nt][reg];
        rs += v;
        rq += v * v;
        hout[(size_t)(n0 + j * 16 + kg * 4 + reg) * 64 + col] = f2bf(v);
      }
      ssum[nt] += rs;
      ssq[nt] += rq;
    }
  }
#pragma unroll
  for (int nt = 0; nt < 4; nt++) {
    ssum[nt] += __shfl_xor(ssum[nt], 16, 64);
    ssum[nt] += __shfl_xor(ssum[nt], 32, 64);
    ssq[nt] += __shfl_xor(ssq[nt], 16, 64);
    ssq[nt] += __shfl_xor(ssq[nt], 32, 64);
  }
  if (lane < 16) {
#pragma unroll
    for (int nt = 0; nt < 4; nt++) {
      psum[(size_t)waveId * 64 + nt * 16 + lane] = ssum[nt];
      psq[(size_t)waveId * 64 + nt * 16 + lane] = ssq[nt];
    }
  }
}

// ---- finalize BN: one block per channel ----
__global__ void bn_finalize(const float* __restrict__ psum, const float* __restrict__ psq,
                            const float* __restrict__ g, const float* __restrict__ b,
                            float* __restrict__ scale, float* __restrict__ shift,
                            float invN, int nw) {
  int c = blockIdx.x;
  float s = 0.f, q = 0.f;
  for (int i = threadIdx.x; i < nw; i += blockDim.x) {
    s += psum[(size_t)i * 64 + c];
    q += psq[(size_t)i * 64 + c];
  }
#pragma unroll
  for (int off = 32; off >= 1; off >>= 1) {
    s += __shfl_down(s, off, 64);
    q += __shfl_down(q, off, 64);
  }
  __shared__ float ls[4], lq[4];
  int wid = threadIdx.x >> 6;
  int lane = threadIdx.x & 63;
  if (lane == 0) { ls[wid] = s; lq[wid] = q; }
  __syncthreads();
  if (threadIdx.x == 0) {
    s = ls[0] + ls[1] + ls[2] + ls[3];
    q = lq[0] + lq[1] + lq[2] + lq[3];
    float mean = s * invN;
    float var = q * invN - mean * mean;
    float rstd = rsqrtf(var + EPSV);
    float sc = rstd * g[c];
    scale[c] = sc;
    shift[c] = b[c] - mean * sc;
  }
}

// ---- y = relu(h*scale + shift) (bf16 -> bf16); preserves zero sentinel row ----
__global__ void bn_relu_apply(const u16* __restrict__ h, const float* __restrict__ scale,
                              const float* __restrict__ shift, u16* __restrict__ y, int n8) {
  int i0 = blockIdx.x * blockDim.x + threadIdx.x;
  int c0 = (i0 * 8) & 63;
  float sc[8], sh[8];
#pragma unroll
  for (int j = 0; j < 8; j++) { sc[j] = scale[c0 + j]; sh[j] = shift[c0 + j]; }
  int stride = gridDim.x * blockDim.x;  // stride*8 multiple of 64 -> c0 invariant
  for (int i = i0; i < n8; i += stride) {
    u16x8 hv = reinterpret_cast<const u16x8*>(h)[i];
    u16x8 o;
#pragma unroll
    for (int j = 0; j < 8; j++) {
      float f = bf2f(hv[j]) * sc[j] + sh[j];
      o[j] = f2bf(fmaxf(f, 0.f));
    }
    reinterpret_cast<u16x8*>(y)[i] = o;
  }
  if (i0 < 8) {  // keep zero sentinel row for conv2's gathers
    u16x8 z;
#pragma unroll
    for (int j = 0; j < 8; j++) z[j] = 0;
    reinterpret_cast<u16x8*>(y)[n8 + i0] = z;
  }
}

// ---- out = relu(h*scale + shift + x) (f32 out) ----
__global__ void bn_add_relu(const u16* __restrict__ h, const float* __restrict__ scale,
                            const float* __restrict__ shift, const float* __restrict__ x,
                            float* __restrict__ out, int n8) {
  int i0 = blockIdx.x * blockDim.x + threadIdx.x;
  int c0 = (i0 * 8) & 63;
  float sc[8], sh[8];
#pragma unroll
  for (int j = 0; j < 8; j++) { sc[j] = scale[c0 + j]; sh[j] = shift[c0 + j]; }
  int stride = gridDim.x * blockDim.x;
  for (int i = i0; i < n8; i += stride) {
    u16x8 hv = reinterpret_cast<const u16x8*>(h)[i];
    const f32x4* xp = reinterpret_cast<const f32x4*>(x) + i * 2;
    f32x4 x0 = xp[0], x1 = xp[1];
    f32x4 o0, o1;
#pragma unroll
    for (int j = 0; j < 4; j++) {
      o0[j] = fmaxf(bf2f(hv[j]) * sc[j] + sh[j] + x0[j], 0.f);
      o1[j] = fmaxf(bf2f(hv[j + 4]) * sc[j + 4] + sh[j + 4] + x1[j], 0.f);
    }
    f32x4* op = reinterpret_cast<f32x4*>(out) + i * 2;
    op[0] = o0;
    op[1] = o1;
  }
}

extern "C" void kernel_launch(void* const* d_in, const int* in_sizes, int n_in,
                              void* d_out, int out_size, void* d_ws, size_t ws_size,
                              hipStream_t stream) {
  const float* x = (const float*)d_in[0];
  const int* nbr = (const int*)d_in[1];
  const int* msk = (const int*)d_in[2];
  const float* W1 = (const float*)d_in[3];
  const float* g1 = (const float*)d_in[4];
  const float* b1 = (const float*)d_in[5];
  const float* W2 = (const float*)d_in[6];
  const float* g2 = (const float*)d_in[7];
  const float* b2 = (const float*)d_in[8];
  float* out = (float*)d_out;

  const int N = in_sizes[0] / 64;     // 800000
  const int nwaves = N / 32;          // 25000 waves, 2 tiles (32 rows) each
  const int nblocks = nwaves / 2;     // 12500 blocks of 2 waves (128 thr)
  const int n8 = N * 8;
  const size_t NC2 = (size_t)N * 64 * 2;      // one bf16 feature map
  const size_t MAPB = NC2 + 256;              // + sentinel row

  char* ws = (char*)d_ws;
  u16* bufA = (u16*)ws;                       // xg (+zero row), then y1 (+zero row)
  u16* bufB = (u16*)(ws + MAPB);              // h1, then h2
  u16* wf = (u16*)(ws + 2 * MAPB);            // 2 * 229376 B of B-fragments
  float* sc = (float*)(ws + 2 * MAPB + 512 * 1024);  // scale1|shift1|scale2|shift2

  // dead d_out space (out = 51.2M floats): cidx_t ints [0, 22.4M),
  // psum/psq at float offsets 30M/33M (consumed before bn_add_relu runs).
  int* cidx_t = (int*)d_out;
  float* psum = (float*)d_out + 30000000;
  float* psq = (float*)d_out + 33000000;

  float invN = 1.0f / (float)N;

  prep_x<<<2048, 256, 0, stream>>>(x, bufA, n8);
  prep_tcidx<<<N / 128, 256, 0, stream>>>(nbr, msk, cidx_t, N);
  prep_w<<<112, 256, 0, stream>>>(W1, W2, wf);
  sconv<<<nblocks, 128, 0, stream>>>(bufA, cidx_t, wf, bufB, psum, psq);
  bn_finalize<<<64, 256, 0, stream>>>(psum, psq, g1, b1, sc, sc + 64, invN, nwaves);
  bn_relu_apply<<<2048, 256, 0, stream>>>(bufB, sc, sc + 64, bufA, n8);
  sconv<<<nblocks, 128, 0, stream>>>(bufA, cidx_t, wf + FRAGS_PER_CONV * 8, bufB, psum, psq);
  bn_finalize<<<64, 256, 0, stream>>>(psum, psq, g2, b2, sc + 128, sc + 192, invN, nwaves);
  bn_add_relu<<<2048, 256, 0, stream>>>(bufB, sc + 128, sc + 192, x, out, n8);
}

// Round 11
// 854.475 us; speedup vs baseline: 1.5128x; 1.5128x over previous
//
#include <hip/hip_runtime.h>

typedef unsigned short u16;
typedef unsigned int u32;
typedef __bf16 bf16x8 __attribute__((ext_vector_type(8)));
typedef u16 u16x8 __attribute__((ext_vector_type(8)));
typedef float f32x4 __attribute__((ext_vector_type(4)));

#define KOFF 27
#define KPAD 28
#define EPSV 1e-5f
#define FRAGS_PER_CONV 14336  // 28 k-slots * 512 fragments (u16x8 units)
#define LDS_S 133             // LDS row stride (ints) for prep_tcidx

__device__ __forceinline__ u16 f2bf(float f) {
  u32 u = __builtin_bit_cast(u32, f);
  u = (u + 0x7FFFu + ((u >> 16) & 1u)) >> 16;
  return (u16)u;
}
__device__ __forceinline__ float bf2f(u16 h) {
  return __builtin_bit_cast(float, (u32)h << 16);
}

// async copy: per-lane global src, LDS dest = uniform base + lane*16, no VGPR dest
__device__ __forceinline__ void gl_lds16(const void* g, void* l) {
  __builtin_amdgcn_global_load_lds(
      (__attribute__((address_space(1))) void*)g,
      (__attribute__((address_space(3))) void*)l, 16, 0, 0);
}

// ---- x (f32) -> bf16, vectorized ----
__global__ void prep_x(const float* __restrict__ x, u16* __restrict__ xg, int n8) {
  int stride = gridDim.x * blockDim.x;
  for (int i = blockIdx.x * blockDim.x + threadIdx.x; i < n8; i += stride) {
    const f32x4* p = reinterpret_cast<const f32x4*>(x) + i * 2;
    f32x4 v0 = p[0], v1 = p[1];
    u16x8 o;
    o[0] = f2bf(v0[0]); o[1] = f2bf(v0[1]); o[2] = f2bf(v0[2]); o[3] = f2bf(v0[3]);
    o[4] = f2bf(v1[0]); o[5] = f2bf(v1[1]); o[6] = f2bf(v1[2]); o[7] = f2bf(v1[3]);
    reinterpret_cast<u16x8*>(xg)[i] = o;
  }
}

// ---- nbr+mask -> tile-major cidx_t[tile][28][16]; -1 = skip; k=27 is pad ----
__global__ __launch_bounds__(256) void prep_tcidx(
    const int* __restrict__ nbr, const int* __restrict__ msk,
    int* __restrict__ cidx_t) {
  __shared__ int lds[27 * LDS_S + 16];
  const int tid = threadIdx.x;
  const int blk = blockIdx.x;
  const int in_base = blk * (128 * KOFF);
#pragma unroll
  for (int it = 0; it < 14; it++) {
    int t = tid + it * 256;
    if (t < 128 * KOFF) {
      int g = in_base + t;
      int v = msk[g] ? nbr[g] : -1;
      int row = (u32)t / KOFF;
      int k = t - row * KOFF;
      lds[k * LDS_S + row] = v;
    }
  }
  __syncthreads();
  const int out_base = blk * (8 * KPAD * 16);
#pragma unroll
  for (int it = 0; it < 14; it++) {
    int o = tid + it * 256;
    int tl = (u32)o / (KPAD * 16);
    int rem = o - tl * (KPAD * 16);
    int k = rem >> 4;
    int r = rem & 15;
    int v = (k < KOFF) ? lds[k * LDS_S + tl * 16 + r] : -1;
    cidx_t[out_base + o] = v;
  }
}

// ---- W1,W2 -> bf16 B-fragments in MFMA lane order; k-slot 27 zeroed ----
__global__ void prep_w(const float* __restrict__ W1, const float* __restrict__ W2,
                       u16* __restrict__ wf) {
  int tid = blockIdx.x * blockDim.x + threadIdx.x;
  if (tid >= 2 * FRAGS_PER_CONV) return;
  int conv = tid / FRAGS_PER_CONV;
  int slot = tid - conv * FRAGS_PER_CONV;
  int k = slot >> 9;
  u16x8 o;
  if (k >= KOFF) {
#pragma unroll
    for (int j = 0; j < 8; j++) o[j] = 0;
  } else {
    const float* src = conv ? W2 : W1;
    int rest = slot & 511;
    int c = rest >> 8;
    int nt = (rest >> 6) & 3;
    int lane = rest & 63;
    int col = nt * 16 + (lane & 15);
    int kk0 = c * 32 + (lane >> 4) * 8;
    int base = k * 4096 + kk0 * 64 + col;
#pragma unroll
    for (int j = 0; j < 8; j++) o[j] = f2bf(src[base + j * 64]);
  }
  reinterpret_cast<u16x8*>(wf)[tid] = o;
}

// ---- sparse conv: r7 structure (4 tiles/wave, rolled k-loop, conditional
// VGPR gathers) + block-shared double-buffered B in LDS: each block stages
// B[k] (8KB) once via global_load_lds; 4 waves read it conflict-free.
// L2 B-traffic /4 vs r7. One __syncthreads per k. ----
__global__ __launch_bounds__(256) void sconv(
    const u16* __restrict__ xg, const int* __restrict__ cidx_t,
    const u16* __restrict__ wf, u16* __restrict__ hout,
    float* __restrict__ psum, float* __restrict__ psq) {
  __shared__ __align__(1024) bf16x8 bsm[2][512];  // 2 x 8KB B double-buffer
  const int lane = threadIdx.x & 63;
  const int r = lane & 15;        // A row within tile / C col within 16-group
  const int kg = lane >> 4;       // channel-group
  const int widInBlk = threadIdx.x >> 6;
  const int waveId = blockIdx.x * 4 + widInBlk;   // grid exact: no guard (barriers)
  const char* wfc = (const char*)wf;
  const int chOff = kg * 8;
  bf16x8 zz;
#pragma unroll
  for (int j = 0; j < 8; j++) zz[j] = (__bf16)0.0f;

  const int n0 = waveId * 64;
  const int* cp[4];
#pragma unroll
  for (int j = 0; j < 4; j++)
    cp[j] = cidx_t + (size_t)(waveId * 4 + j) * (KPAD * 16) + r;

  f32x4 acc[4][4];  // [tile][nt], constant indexing only
#pragma unroll
  for (int j = 0; j < 4; j++)
#pragma unroll
    for (int nt = 0; nt < 4; nt++) {
      acc[j][nt][0] = 0.f; acc[j][nt][1] = 0.f;
      acc[j][nt][2] = 0.f; acc[j][nt][3] = 0.f;
    }

// block-cooperative stage of B[ks] (8KB) into buffer bc: per wave 2 x 1KB
#define STAGEB(bc, ks)                                                     \
  {                                                                        \
    const char* s = wfc + ((size_t)(ks) << 13) + widInBlk * 1024 + lane * 16; \
    char* d = (char*)&bsm[bc][0] + widInBlk * 1024 + lane * 16;            \
    gl_lds16(s, d);                                                        \
    gl_lds16(s + 4096, d + 4096);                                          \
  }

  STAGEB(0, 0);  // prologue: B[0] in flight

  for (int k = 0; k < KOFF; k++) {
    // drain our stage ops (gathers from k-1 already consumed by MFMAs),
    // then block-sync so all 4 waves' stage of B[k] is visible.
    asm volatile("s_waitcnt vmcnt(0)" ::: "memory");
    __syncthreads();
    if (k + 1 < KOFF) STAGEB((k + 1) & 1, k + 1);  // async, no dest regs

    int id[4];
#pragma unroll
    for (int j = 0; j < 4; j++) id[j] = cp[j][k << 4];
    bf16x8 a0[4], a1[4];
#pragma unroll
    for (int j = 0; j < 4; j++) {
      a0[j] = zz; a1[j] = zz;
      if (id[j] >= 0) {
        const bf16x8* ap =
            reinterpret_cast<const bf16x8*>(xg + ((size_t)id[j] << 6) + chOff);
        a0[j] = ap[0];
        a1[j] = ap[4];
      }
    }
    const bf16x8* bl = &bsm[k & 1][0];
#pragma unroll
    for (int nt = 0; nt < 4; nt++) {
      bf16x8 b = bl[nt * 64 + lane];
#pragma unroll
      for (int j = 0; j < 4; j++)
        acc[j][nt] = __builtin_amdgcn_mfma_f32_16x16x32_bf16(a0[j], b, acc[j][nt], 0, 0, 0);
    }
#pragma unroll
    for (int nt = 0; nt < 4; nt++) {
      bf16x8 b = bl[256 + nt * 64 + lane];
#pragma unroll
      for (int j = 0; j < 4; j++)
        acc[j][nt] = __builtin_amdgcn_mfma_f32_16x16x32_bf16(a1[j], b, acc[j][nt], 0, 0, 0);
    }
  }
#undef STAGEB

  // C/D layout: col = lane&15 (+16*nt), row = kg*4 + reg (+16*tile)
  float ssum[4] = {0.f, 0.f, 0.f, 0.f};
  float ssq[4] = {0.f, 0.f, 0.f, 0.f};
#pragma unroll
  for (int j = 0; j < 4; j++) {
#pragma unroll
    for (int nt = 0; nt < 4; nt++) {
      const int col = nt * 16 + r;
      float rs = 0.f, rq = 0.f;
#pragma unroll
      for (int reg = 0; reg < 4; reg++) {
        float v = acc[j][nt][reg];
        rs += v;
        rq += v * v;
        hout[(size_t)(n0 + j * 16 + kg * 4 + reg) * 64 + col] = f2bf(v);
      }
      ssum[nt] += rs;
      ssq[nt] += rq;
    }
  }
#pragma unroll
  for (int nt = 0; nt < 4; nt++) {
    ssum[nt] += __shfl_xor(ssum[nt], 16, 64);
    ssum[nt] += __shfl_xor(ssum[nt], 32, 64);
    ssq[nt] += __shfl_xor(ssq[nt], 16, 64);
    ssq[nt] += __shfl_xor(ssq[nt], 32, 64);
  }
  if (lane < 16) {
#pragma unroll
    for (int nt = 0; nt < 4; nt++) {
      psum[(size_t)waveId * 64 + nt * 16 + lane] = ssum[nt];
      psq[(size_t)waveId * 64 + nt * 16 + lane] = ssq[nt];
    }
  }
}

// ---- finalize BN: one block per channel ----
__global__ void bn_finalize(const float* __restrict__ psum, const float* __restrict__ psq,
                            const float* __restrict__ g, const float* __restrict__ b,
                            float* __restrict__ scale, float* __restrict__ shift,
                            float invN, int nw) {
  int c = blockIdx.x;
  float s = 0.f, q = 0.f;
  for (int i = threadIdx.x; i < nw; i += blockDim.x) {
    s += psum[(size_t)i * 64 + c];
    q += psq[(size_t)i * 64 + c];
  }
#pragma unroll
  for (int off = 32; off >= 1; off >>= 1) {
    s += __shfl_down(s, off, 64);
    q += __shfl_down(q, off, 64);
  }
  __shared__ float ls[4], lq[4];
  int wid = threadIdx.x >> 6;
  int lane = threadIdx.x & 63;
  if (lane == 0) { ls[wid] = s; lq[wid] = q; }
  __syncthreads();
  if (threadIdx.x == 0) {
    s = ls[0] + ls[1] + ls[2] + ls[3];
    q = lq[0] + lq[1] + lq[2] + lq[3];
    float mean = s * invN;
    float var = q * invN - mean * mean;
    float rstd = rsqrtf(var + EPSV);
    float sc = rstd * g[c];
    scale[c] = sc;
    shift[c] = b[c] - mean * sc;
  }
}

// ---- y = relu(h*scale + shift) (bf16 -> bf16) ----
__global__ void bn_relu_apply(const u16* __restrict__ h, const float* __restrict__ scale,
                              const float* __restrict__ shift, u16* __restrict__ y, int n8) {
  int i0 = blockIdx.x * blockDim.x + threadIdx.x;
  int c0 = (i0 * 8) & 63;
  float sc[8], sh[8];
#pragma unroll
  for (int j = 0; j < 8; j++) { sc[j] = scale[c0 + j]; sh[j] = shift[c0 + j]; }
  int stride = gridDim.x * blockDim.x;  // stride*8 multiple of 64 -> c0 invariant
  for (int i = i0; i < n8; i += stride) {
    u16x8 hv = reinterpret_cast<const u16x8*>(h)[i];
    u16x8 o;
#pragma unroll
    for (int j = 0; j < 8; j++) {
      float f = bf2f(hv[j]) * sc[j] + sh[j];
      o[j] = f2bf(fmaxf(f, 0.f));
    }
    reinterpret_cast<u16x8*>(y)[i] = o;
  }
}

// ---- out = relu(h*scale + shift + x) (f32 out) ----
__global__ void bn_add_relu(const u16* __restrict__ h, const float* __restrict__ scale,
                            const float* __restrict__ shift, const float* __restrict__ x,
                            float* __restrict__ out, int n8) {
  int i0 = blockIdx.x * blockDim.x + threadIdx.x;
  int c0 = (i0 * 8) & 63;
  float sc[8], sh[8];
#pragma unroll
  for (int j = 0; j < 8; j++) { sc[j] = scale[c0 + j]; sh[j] = shift[c0 + j]; }
  int stride = gridDim.x * blockDim.x;
  for (int i = i0; i < n8; i += stride) {
    u16x8 hv = reinterpret_cast<const u16x8*>(h)[i];
    const f32x4* xp = reinterpret_cast<const f32x4*>(x) + i * 2;
    f32x4 x0 = xp[0], x1 = xp[1];
    f32x4 o0, o1;
#pragma unroll
    for (int j = 0; j < 4; j++) {
      o0[j] = fmaxf(bf2f(hv[j]) * sc[j] + sh[j] + x0[j], 0.f);
      o1[j] = fmaxf(bf2f(hv[j + 4]) * sc[j + 4] + sh[j + 4] + x1[j], 0.f);
    }
    f32x4* op = reinterpret_cast<f32x4*>(out) + i * 2;
    op[0] = o0;
    op[1] = o1;
  }
}

extern "C" void kernel_launch(void* const* d_in, const int* in_sizes, int n_in,
                              void* d_out, int out_size, void* d_ws, size_t ws_size,
                              hipStream_t stream) {
  const float* x = (const float*)d_in[0];
  const int* nbr = (const int*)d_in[1];
  const int* msk = (const int*)d_in[2];
  const float* W1 = (const float*)d_in[3];
  const float* g1 = (const float*)d_in[4];
  const float* b1 = (const float*)d_in[5];
  const float* W2 = (const float*)d_in[6];
  const float* g2 = (const float*)d_in[7];
  const float* b2 = (const float*)d_in[8];
  float* out = (float*)d_out;

  const int N = in_sizes[0] / 64;     // 800000
  const int nquads = N / 64;          // 12500 waves, 1 quad (64 rows) each
  const int nblocks = nquads / 4;     // 3125 blocks of 4 waves (grid exact)
  const int n8 = N * 8;
  const size_t NC2 = (size_t)N * 64 * 2;      // one bf16 feature map
  const size_t MAPB = NC2 + 256;

  char* ws = (char*)d_ws;
  u16* bufA = (u16*)ws;                       // xg, then y1
  u16* bufB = (u16*)(ws + MAPB);              // h1, then h2
  u16* wf = (u16*)(ws + 2 * MAPB);            // 2 * 229376 B of B-fragments
  float* psum = (float*)(ws + 2 * MAPB + 512 * 1024);
  float* psq = psum + (size_t)nquads * 64;
  float* sc = psq + (size_t)nquads * 64;      // scale1|shift1|scale2|shift2

  // cidx_t ([N/16][28][16] ints, 89.6 MB) lives in d_out: dead until
  // bn_add_relu, which runs last and fully overwrites d_out.
  int* cidx_t = (int*)d_out;

  float invN = 1.0f / (float)N;

  prep_x<<<2048, 256, 0, stream>>>(x, bufA, n8);
  prep_tcidx<<<N / 128, 256, 0, stream>>>(nbr, msk, cidx_t);
  prep_w<<<112, 256, 0, stream>>>(W1, W2, wf);
  sconv<<<nblocks, 256, 0, stream>>>(bufA, cidx_t, wf, bufB, psum, psq);
  bn_finalize<<<64, 256, 0, stream>>>(psum, psq, g1, b1, sc, sc + 64, invN, nquads);
  bn_relu_apply<<<2048, 256, 0, stream>>>(bufB, sc, sc + 64, bufA, n8);
  sconv<<<nblocks, 256, 0, stream>>>(bufA, cidx_t, wf + FRAGS_PER_CONV * 8, bufB, psum, psq);
  bn_finalize<<<64, 256, 0, stream>>>(psum, psq, g2, b2, sc + 128, sc + 192, invN, nquads);
  bn_add_relu<<<2048, 256, 0, stream>>>(bufB, sc + 128, sc + 192, x, out, n8);
}

// Round 12
// 844.562 us; speedup vs baseline: 1.5306x; 1.0117x over previous
//
#include <hip/hip_runtime.h>

typedef unsigned short u16;
typedef unsigned int u32;
typedef __bf16 bf16x8 __attribute__((ext_vector_type(8)));
typedef u16 u16x8 __attribute__((ext_vector_type(8)));
typedef float f32x4 __attribute__((ext_vector_type(4)));

#define KOFF 27
#define KPAD 28
#define EPSV 1e-5f
#define FRAGS_PER_CONV 14336  // 28 k-slots * 512 fragments (u16x8 units)
#define LDS_S 133             // LDS row stride (ints) for prep_tcidx

__device__ __forceinline__ u16 f2bf(float f) {
  u32 u = __builtin_bit_cast(u32, f);
  u = (u + 0x7FFFu + ((u >> 16) & 1u)) >> 16;
  return (u16)u;
}
__device__ __forceinline__ float bf2f(u16 h) {
  return __builtin_bit_cast(float, (u32)h << 16);
}

// async copy: per-lane global src, LDS dest = uniform base + lane*16, no VGPR dest
__device__ __forceinline__ void gl_lds16(const void* g, void* l) {
  __builtin_amdgcn_global_load_lds(
      (__attribute__((address_space(1))) void*)g,
      (__attribute__((address_space(3))) void*)l, 16, 0, 0);
}

// ---- x (f32) -> bf16, vectorized ----
__global__ void prep_x(const float* __restrict__ x, u16* __restrict__ xg, int n8) {
  int stride = gridDim.x * blockDim.x;
  for (int i = blockIdx.x * blockDim.x + threadIdx.x; i < n8; i += stride) {
    const f32x4* p = reinterpret_cast<const f32x4*>(x) + i * 2;
    f32x4 v0 = p[0], v1 = p[1];
    u16x8 o;
    o[0] = f2bf(v0[0]); o[1] = f2bf(v0[1]); o[2] = f2bf(v0[2]); o[3] = f2bf(v0[3]);
    o[4] = f2bf(v1[0]); o[5] = f2bf(v1[1]); o[6] = f2bf(v1[2]); o[7] = f2bf(v1[3]);
    reinterpret_cast<u16x8*>(xg)[i] = o;
  }
}

// ---- nbr+mask -> tile-major cidx_t[tile][28][16]; -1 = skip; k=27 is pad ----
__global__ __launch_bounds__(256) void prep_tcidx(
    const int* __restrict__ nbr, const int* __restrict__ msk,
    int* __restrict__ cidx_t) {
  __shared__ int lds[27 * LDS_S + 16];
  const int tid = threadIdx.x;
  const int blk = blockIdx.x;
  const int in_base = blk * (128 * KOFF);
#pragma unroll
  for (int it = 0; it < 14; it++) {
    int t = tid + it * 256;
    if (t < 128 * KOFF) {
      int g = in_base + t;
      int v = msk[g] ? nbr[g] : -1;
      int row = (u32)t / KOFF;
      int k = t - row * KOFF;
      lds[k * LDS_S + row] = v;
    }
  }
  __syncthreads();
  const int out_base = blk * (8 * KPAD * 16);
#pragma unroll
  for (int it = 0; it < 14; it++) {
    int o = tid + it * 256;
    int tl = (u32)o / (KPAD * 16);
    int rem = o - tl * (KPAD * 16);
    int k = rem >> 4;
    int r = rem & 15;
    int v = (k < KOFF) ? lds[k * LDS_S + tl * 16 + r] : -1;
    cidx_t[out_base + o] = v;
  }
}

// ---- W1,W2 -> bf16 B-fragments in MFMA lane order; k-slot 27 zeroed ----
__global__ void prep_w(const float* __restrict__ W1, const float* __restrict__ W2,
                       u16* __restrict__ wf) {
  int tid = blockIdx.x * blockDim.x + threadIdx.x;
  if (tid >= 2 * FRAGS_PER_CONV) return;
  int conv = tid / FRAGS_PER_CONV;
  int slot = tid - conv * FRAGS_PER_CONV;
  int k = slot >> 9;
  u16x8 o;
  if (k >= KOFF) {
#pragma unroll
    for (int j = 0; j < 8; j++) o[j] = 0;
  } else {
    const float* src = conv ? W2 : W1;
    int rest = slot & 511;
    int c = rest >> 8;
    int nt = (rest >> 6) & 3;
    int lane = rest & 63;
    int col = nt * 16 + (lane & 15);
    int kk0 = c * 32 + (lane >> 4) * 8;
    int base = k * 4096 + kk0 * 64 + col;
#pragma unroll
    for (int j = 0; j < 8; j++) o[j] = f2bf(src[base + j * 64]);
  }
  reinterpret_cast<u16x8*>(wf)[tid] = o;
}

// ---- sparse conv: r11 structure (4 tiles/wave, rolled k-loop, conditional
// VGPR gathers, block-shared double-buffered B in LDS) with
// __launch_bounds__(256,4): cap combined regs at 128 (VGPR<=64 + 64 AGPR acc)
// -> 4 waves/SIMD instead of 3. ----
__global__ __launch_bounds__(256, 4) void sconv(
    const u16* __restrict__ xg, const int* __restrict__ cidx_t,
    const u16* __restrict__ wf, u16* __restrict__ hout,
    float* __restrict__ psum, float* __restrict__ psq) {
  __shared__ __align__(1024) bf16x8 bsm[2][512];  // 2 x 8KB B double-buffer
  const int lane = threadIdx.x & 63;
  const int r = lane & 15;        // A row within tile / C col within 16-group
  const int kg = lane >> 4;       // channel-group
  const int widInBlk = threadIdx.x >> 6;
  const int waveId = blockIdx.x * 4 + widInBlk;   // grid exact: no guard (barriers)
  const char* wfc = (const char*)wf;
  const int chOff = kg * 8;
  bf16x8 zz;
#pragma unroll
  for (int j = 0; j < 8; j++) zz[j] = (__bf16)0.0f;

  const int n0 = waveId * 64;
  const int* cp[4];
#pragma unroll
  for (int j = 0; j < 4; j++)
    cp[j] = cidx_t + (size_t)(waveId * 4 + j) * (KPAD * 16) + r;

  f32x4 acc[4][4];  // [tile][nt], constant indexing only
#pragma unroll
  for (int j = 0; j < 4; j++)
#pragma unroll
    for (int nt = 0; nt < 4; nt++) {
      acc[j][nt][0] = 0.f; acc[j][nt][1] = 0.f;
      acc[j][nt][2] = 0.f; acc[j][nt][3] = 0.f;
    }

// block-cooperative stage of B[ks] (8KB) into buffer bc: per wave 2 x 1KB
#define STAGEB(bc, ks)                                                     \
  {                                                                        \
    const char* s = wfc + ((size_t)(ks) << 13) + widInBlk * 1024 + lane * 16; \
    char* d = (char*)&bsm[bc][0] + widInBlk * 1024 + lane * 16;            \
    gl_lds16(s, d);                                                        \
    gl_lds16(s + 4096, d + 4096);                                          \
  }

  STAGEB(0, 0);  // prologue: B[0] in flight

  for (int k = 0; k < KOFF; k++) {
    // drain our stage ops (gathers from k-1 already consumed by MFMAs),
    // then block-sync so all 4 waves' stage of B[k] is visible.
    asm volatile("s_waitcnt vmcnt(0)" ::: "memory");
    __syncthreads();
    if (k + 1 < KOFF) STAGEB((k + 1) & 1, k + 1);  // async, no dest regs

    int id[4];
#pragma unroll
    for (int j = 0; j < 4; j++) id[j] = cp[j][k << 4];
    bf16x8 a0[4], a1[4];
#pragma unroll
    for (int j = 0; j < 4; j++) {
      a0[j] = zz; a1[j] = zz;
      if (id[j] >= 0) {
        const bf16x8* ap =
            reinterpret_cast<const bf16x8*>(xg + ((size_t)id[j] << 6) + chOff);
        a0[j] = ap[0];
        a1[j] = ap[4];
      }
    }
    const bf16x8* bl = &bsm[k & 1][0];
#pragma unroll
    for (int nt = 0; nt < 4; nt++) {
      bf16x8 b = bl[nt * 64 + lane];
#pragma unroll
      for (int j = 0; j < 4; j++)
        acc[j][nt] = __builtin_amdgcn_mfma_f32_16x16x32_bf16(a0[j], b, acc[j][nt], 0, 0, 0);
    }
#pragma unroll
    for (int nt = 0; nt < 4; nt++) {
      bf16x8 b = bl[256 + nt * 64 + lane];
#pragma unroll
      for (int j = 0; j < 4; j++)
        acc[j][nt] = __builtin_amdgcn_mfma_f32_16x16x32_bf16(a1[j], b, acc[j][nt], 0, 0, 0);
    }
  }
#undef STAGEB

  // C/D layout: col = lane&15 (+16*nt), row = kg*4 + reg (+16*tile)
  float ssum[4] = {0.f, 0.f, 0.f, 0.f};
  float ssq[4] = {0.f, 0.f, 0.f, 0.f};
#pragma unroll
  for (int j = 0; j < 4; j++) {
#pragma unroll
    for (int nt = 0; nt < 4; nt++) {
      const int col = nt * 16 + r;
      float rs = 0.f, rq = 0.f;
#pragma unroll
      for (int reg = 0; reg < 4; reg++) {
        float v = acc[j][nt][reg];
        rs += v;
        rq += v * v;
        hout[(size_t)(n0 + j * 16 + kg * 4 + reg) * 64 + col] = f2bf(v);
      }
      ssum[nt] += rs;
      ssq[nt] += rq;
    }
  }
#pragma unroll
  for (int nt = 0; nt < 4; nt++) {
    ssum[nt] += __shfl_xor(ssum[nt], 16, 64);
    ssum[nt] += __shfl_xor(ssum[nt], 32, 64);
    ssq[nt] += __shfl_xor(ssq[nt], 16, 64);
    ssq[nt] += __shfl_xor(ssq[nt], 32, 64);
  }
  if (lane < 16) {
#pragma unroll
    for (int nt = 0; nt < 4; nt++) {
      psum[(size_t)waveId * 64 + nt * 16 + lane] = ssum[nt];
      psq[(size_t)waveId * 64 + nt * 16 + lane] = ssq[nt];
    }
  }
}

// ---- finalize BN: one block per channel ----
__global__ void bn_finalize(const float* __restrict__ psum, const float* __restrict__ psq,
                            const float* __restrict__ g, const float* __restrict__ b,
                            float* __restrict__ scale, float* __restrict__ shift,
                            float invN, int nw) {
  int c = blockIdx.x;
  float s = 0.f, q = 0.f;
  for (int i = threadIdx.x; i < nw; i += blockDim.x) {
    s += psum[(size_t)i * 64 + c];
    q += psq[(size_t)i * 64 + c];
  }
#pragma unroll
  for (int off = 32; off >= 1; off >>= 1) {
    s += __shfl_down(s, off, 64);
    q += __shfl_down(q, off, 64);
  }
  __shared__ float ls[4], lq[4];
  int wid = threadIdx.x >> 6;
  int lane = threadIdx.x & 63;
  if (lane == 0) { ls[wid] = s; lq[wid] = q; }
  __syncthreads();
  if (threadIdx.x == 0) {
    s = ls[0] + ls[1] + ls[2] + ls[3];
    q = lq[0] + lq[1] + lq[2] + lq[3];
    float mean = s * invN;
    float var = q * invN - mean * mean;
    float rstd = rsqrtf(var + EPSV);
    float sc = rstd * g[c];
    scale[c] = sc;
    shift[c] = b[c] - mean * sc;
  }
}

// ---- y = relu(h*scale + shift) (bf16 -> bf16) ----
__global__ void bn_relu_apply(const u16* __restrict__ h, const float* __restrict__ scale,
                              const float* __restrict__ shift, u16* __restrict__ y, int n8) {
  int i0 = blockIdx.x * blockDim.x + threadIdx.x;
  int c0 = (i0 * 8) & 63;
  float sc[8], sh[8];
#pragma unroll
  for (int j = 0; j < 8; j++) { sc[j] = scale[c0 + j]; sh[j] = shift[c0 + j]; }
  int stride = gridDim.x * blockDim.x;  // stride*8 multiple of 64 -> c0 invariant
  for (int i = i0; i < n8; i += stride) {
    u16x8 hv = reinterpret_cast<const u16x8*>(h)[i];
    u16x8 o;
#pragma unroll
    for (int j = 0; j < 8; j++) {
      float f = bf2f(hv[j]) * sc[j] + sh[j];
      o[j] = f2bf(fmaxf(f, 0.f));
    }
    reinterpret_cast<u16x8*>(y)[i] = o;
  }
}

// ---- out = relu(h*scale + shift + x) (f32 out) ----
__global__ void bn_add_relu(const u16* __restrict__ h, const float* __restrict__ scale,
                            const float* __restrict__ shift, const float* __restrict__ x,
                            float* __restrict__ out, int n8) {
  int i0 = blockIdx.x * blockDim.x + threadIdx.x;
  int c0 = (i0 * 8) & 63;
  float sc[8], sh[8];
#pragma unroll
  for (int j = 0; j < 8; j++) { sc[j] = scale[c0 + j]; sh[j] = shift[c0 + j]; }
  int stride = gridDim.x * blockDim.x;
  for (int i = i0; i < n8; i += stride) {
    u16x8 hv = reinterpret_cast<const u16x8*>(h)[i];
    const f32x4* xp = reinterpret_cast<const f32x4*>(x) + i * 2;
    f32x4 x0 = xp[0], x1 = xp[1];
    f32x4 o0, o1;
#pragma unroll
    for (int j = 0; j < 4; j++) {
      o0[j] = fmaxf(bf2f(hv[j]) * sc[j] + sh[j] + x0[j], 0.f);
      o1[j] = fmaxf(bf2f(hv[j + 4]) * sc[j + 4] + sh[j + 4] + x1[j], 0.f);
    }
    f32x4* op = reinterpret_cast<f32x4*>(out) + i * 2;
    op[0] = o0;
    op[1] = o1;
  }
}

extern "C" void kernel_launch(void* const* d_in, const int* in_sizes, int n_in,
                              void* d_out, int out_size, void* d_ws, size_t ws_size,
                              hipStream_t stream) {
  const float* x = (const float*)d_in[0];
  const int* nbr = (const int*)d_in[1];
  const int* msk = (const int*)d_in[2];
  const float* W1 = (const float*)d_in[3];
  const float* g1 = (const float*)d_in[4];
  const float* b1 = (const float*)d_in[5];
  const float* W2 = (const float*)d_in[6];
  const float* g2 = (const float*)d_in[7];
  const float* b2 = (const float*)d_in[8];
  float* out = (float*)d_out;

  const int N = in_sizes[0] / 64;     // 800000
  const int nquads = N / 64;          // 12500 waves, 1 quad (64 rows) each
  const int nblocks = nquads / 4;     // 3125 blocks of 4 waves (grid exact)
  const int n8 = N * 8;
  const size_t NC2 = (size_t)N * 64 * 2;      // one bf16 feature map
  const size_t MAPB = NC2 + 256;

  char* ws = (char*)d_ws;
  u16* bufA = (u16*)ws;                       // xg, then y1
  u16* bufB = (u16*)(ws + MAPB);              // h1, then h2
  u16* wf = (u16*)(ws + 2 * MAPB);            // 2 * 229376 B of B-fragments
  float* psum = (float*)(ws + 2 * MAPB + 512 * 1024);
  float* psq = psum + (size_t)nquads * 64;
  float* sc = psq + (size_t)nquads * 64;      // scale1|shift1|scale2|shift2

  // cidx_t ([N/16][28][16] ints, 89.6 MB) lives in d_out: dead until
  // bn_add_relu, which runs last and fully overwrites d_out.
  int* cidx_t = (int*)d_out;

  float invN = 1.0f / (float)N;

  prep_x<<<2048, 256, 0, stream>>>(x, bufA, n8);
  prep_tcidx<<<N / 128, 256, 0, stream>>>(nbr, msk, cidx_t);
  prep_w<<<112, 256, 0, stream>>>(W1, W2, wf);
  sconv<<<nblocks, 256, 0, stream>>>(bufA, cidx_t, wf, bufB, psum, psq);
  bn_finalize<<<64, 256, 0, stream>>>(psum, psq, g1, b1, sc, sc + 64, invN, nquads);
  bn_relu_apply<<<2048, 256, 0, stream>>>(bufB, sc, sc + 64, bufA, n8);
  sconv<<<nblocks, 256, 0, stream>>>(bufA, cidx_t, wf + FRAGS_PER_CONV * 8, bufB, psum, psq);
  bn_finalize<<<64, 256, 0, stream>>>(psum, psq, g2, b2, sc + 128, sc + 192, invN, nquads);
  bn_add_relu<<<2048, 256, 0, stream>>>(bufB, sc + 128, sc + 192, x, out, n8);
}

// Round 13
// 842.777 us; speedup vs baseline: 1.5338x; 1.0021x over previous
//
#include <hip/hip_runtime.h>

typedef unsigned short u16;
typedef unsigned int u32;
typedef __bf16 bf16x8 __attribute__((ext_vector_type(8)));
typedef u16 u16x8 __attribute__((ext_vector_type(8)));
typedef float f32x4 __attribute__((ext_vector_type(4)));

#define KOFF 27
#define KPAD 28
#define EPSV 1e-5f
#define FRAGS_PER_CONV 14336  // 28 k-slots * 512 fragments (u16x8 units)
#define LDS_S 133             // LDS row stride (ints) for prep_tcidx

__device__ __forceinline__ u16 f2bf(float f) {
  u32 u = __builtin_bit_cast(u32, f);
  u = (u + 0x7FFFu + ((u >> 16) & 1u)) >> 16;
  return (u16)u;
}
__device__ __forceinline__ float bf2f(u16 h) {
  return __builtin_bit_cast(float, (u32)h << 16);
}

// async copy: per-lane global src, LDS dest = uniform base + lane*16, no VGPR dest
__device__ __forceinline__ void gl_lds16(const void* g, void* l) {
  __builtin_amdgcn_global_load_lds(
      (__attribute__((address_space(1))) void*)g,
      (__attribute__((address_space(3))) void*)l, 16, 0, 0);
}

// ---- x (f32) -> bf16, vectorized ----
__global__ void prep_x(const float* __restrict__ x, u16* __restrict__ xg, int n8) {
  int stride = gridDim.x * blockDim.x;
  for (int i = blockIdx.x * blockDim.x + threadIdx.x; i < n8; i += stride) {
    const f32x4* p = reinterpret_cast<const f32x4*>(x) + i * 2;
    f32x4 v0 = p[0], v1 = p[1];
    u16x8 o;
    o[0] = f2bf(v0[0]); o[1] = f2bf(v0[1]); o[2] = f2bf(v0[2]); o[3] = f2bf(v0[3]);
    o[4] = f2bf(v1[0]); o[5] = f2bf(v1[1]); o[6] = f2bf(v1[2]); o[7] = f2bf(v1[3]);
    reinterpret_cast<u16x8*>(xg)[i] = o;
  }
}

// ---- nbr+mask -> tile-major cidx_t[tile][28][16]; -1 = skip; k=27 is pad ----
// nt loads (172MB never re-read) + nt stores (full-line coalesced) keep the
// L3 free for the gather-target feature map.
__global__ __launch_bounds__(256) void prep_tcidx(
    const int* __restrict__ nbr, const int* __restrict__ msk,
    int* __restrict__ cidx_t) {
  __shared__ int lds[27 * LDS_S + 16];
  const int tid = threadIdx.x;
  const int blk = blockIdx.x;
  const int in_base = blk * (128 * KOFF);
#pragma unroll
  for (int it = 0; it < 14; it++) {
    int t = tid + it * 256;
    if (t < 128 * KOFF) {
      int g = in_base + t;
      int m = __builtin_nontemporal_load(msk + g);
      int nb = __builtin_nontemporal_load(nbr + g);
      int v = m ? nb : -1;
      int row = (u32)t / KOFF;
      int k = t - row * KOFF;
      lds[k * LDS_S + row] = v;
    }
  }
  __syncthreads();
  const int out_base = blk * (8 * KPAD * 16);
#pragma unroll
  for (int it = 0; it < 14; it++) {
    int o = tid + it * 256;
    int tl = (u32)o / (KPAD * 16);
    int rem = o - tl * (KPAD * 16);
    int k = rem >> 4;
    int r = rem & 15;
    int v = (k < KOFF) ? lds[k * LDS_S + tl * 16 + r] : -1;
    __builtin_nontemporal_store(v, cidx_t + out_base + o);
  }
}

// ---- W1,W2 -> bf16 B-fragments in MFMA lane order; k-slot 27 zeroed ----
__global__ void prep_w(const float* __restrict__ W1, const float* __restrict__ W2,
                       u16* __restrict__ wf) {
  int tid = blockIdx.x * blockDim.x + threadIdx.x;
  if (tid >= 2 * FRAGS_PER_CONV) return;
  int conv = tid / FRAGS_PER_CONV;
  int slot = tid - conv * FRAGS_PER_CONV;
  int k = slot >> 9;
  u16x8 o;
  if (k >= KOFF) {
#pragma unroll
    for (int j = 0; j < 8; j++) o[j] = 0;
  } else {
    const float* src = conv ? W2 : W1;
    int rest = slot & 511;
    int c = rest >> 8;
    int nt = (rest >> 6) & 3;
    int lane = rest & 63;
    int col = nt * 16 + (lane & 15);
    int kk0 = c * 32 + (lane >> 4) * 8;
    int base = k * 4096 + kk0 * 64 + col;
#pragma unroll
    for (int j = 0; j < 8; j++) o[j] = f2bf(src[base + j * 64]);
  }
  reinterpret_cast<u16x8*>(wf)[tid] = o;
}

// ---- sparse conv: r12 structure (4 tiles/wave, rolled k-loop, conditional
// VGPR gathers, block-shared double-buffered B in LDS, launch_bounds(256,4));
// cidx index stream read nontemporal so it never evicts the map from L3. ----
__global__ __launch_bounds__(256, 4) void sconv(
    const u16* __restrict__ xg, const int* __restrict__ cidx_t,
    const u16* __restrict__ wf, u16* __restrict__ hout,
    float* __restrict__ psum, float* __restrict__ psq) {
  __shared__ __align__(1024) bf16x8 bsm[2][512];  // 2 x 8KB B double-buffer
  const int lane = threadIdx.x & 63;
  const int r = lane & 15;        // A row within tile / C col within 16-group
  const int kg = lane >> 4;       // channel-group
  const int widInBlk = threadIdx.x >> 6;
  const int waveId = blockIdx.x * 4 + widInBlk;   // grid exact: no guard (barriers)
  const char* wfc = (const char*)wf;
  const int chOff = kg * 8;
  bf16x8 zz;
#pragma unroll
  for (int j = 0; j < 8; j++) zz[j] = (__bf16)0.0f;

  const int n0 = waveId * 64;
  const int* cp[4];
#pragma unroll
  for (int j = 0; j < 4; j++)
    cp[j] = cidx_t + (size_t)(waveId * 4 + j) * (KPAD * 16) + r;

  f32x4 acc[4][4];  // [tile][nt], constant indexing only
#pragma unroll
  for (int j = 0; j < 4; j++)
#pragma unroll
    for (int nt = 0; nt < 4; nt++) {
      acc[j][nt][0] = 0.f; acc[j][nt][1] = 0.f;
      acc[j][nt][2] = 0.f; acc[j][nt][3] = 0.f;
    }

// block-cooperative stage of B[ks] (8KB) into buffer bc: per wave 2 x 1KB
#define STAGEB(bc, ks)                                                     \
  {                                                                        \
    const char* s = wfc + ((size_t)(ks) << 13) + widInBlk * 1024 + lane * 16; \
    char* d = (char*)&bsm[bc][0] + widInBlk * 1024 + lane * 16;            \
    gl_lds16(s, d);                                                        \
    gl_lds16(s + 4096, d + 4096);                                          \
  }

  STAGEB(0, 0);  // prologue: B[0] in flight

  for (int k = 0; k < KOFF; k++) {
    // drain our stage ops (gathers from k-1 already consumed by MFMAs),
    // then block-sync so all 4 waves' stage of B[k] is visible.
    asm volatile("s_waitcnt vmcnt(0)" ::: "memory");
    __syncthreads();
    if (k + 1 < KOFF) STAGEB((k + 1) & 1, k + 1);  // async, no dest regs

    int id[4];
#pragma unroll
    for (int j = 0; j < 4; j++)
      id[j] = __builtin_nontemporal_load(&cp[j][k << 4]);
    bf16x8 a0[4], a1[4];
#pragma unroll
    for (int j = 0; j < 4; j++) {
      a0[j] = zz; a1[j] = zz;
      if (id[j] >= 0) {
        const bf16x8* ap =
            reinterpret_cast<const bf16x8*>(xg + ((size_t)id[j] << 6) + chOff);
        a0[j] = ap[0];
        a1[j] = ap[4];
      }
    }
    const bf16x8* bl = &bsm[k & 1][0];
#pragma unroll
    for (int nt = 0; nt < 4; nt++) {
      bf16x8 b = bl[nt * 64 + lane];
#pragma unroll
      for (int j = 0; j < 4; j++)
        acc[j][nt] = __builtin_amdgcn_mfma_f32_16x16x32_bf16(a0[j], b, acc[j][nt], 0, 0, 0);
    }
#pragma unroll
    for (int nt = 0; nt < 4; nt++) {
      bf16x8 b = bl[256 + nt * 64 + lane];
#pragma unroll
      for (int j = 0; j < 4; j++)
        acc[j][nt] = __builtin_amdgcn_mfma_f32_16x16x32_bf16(a1[j], b, acc[j][nt], 0, 0, 0);
    }
  }
#undef STAGEB

  // C/D layout: col = lane&15 (+16*nt), row = kg*4 + reg (+16*tile)
  float ssum[4] = {0.f, 0.f, 0.f, 0.f};
  float ssq[4] = {0.f, 0.f, 0.f, 0.f};
#pragma unroll
  for (int j = 0; j < 4; j++) {
#pragma unroll
    for (int nt = 0; nt < 4; nt++) {
      const int col = nt * 16 + r;
      float rs = 0.f, rq = 0.f;
#pragma unroll
      for (int reg = 0; reg < 4; reg++) {
        float v = acc[j][nt][reg];
        rs += v;
        rq += v * v;
        hout[(size_t)(n0 + j * 16 + kg * 4 + reg) * 64 + col] = f2bf(v);
      }
      ssum[nt] += rs;
      ssq[nt] += rq;
    }
  }
#pragma unroll
  for (int nt = 0; nt < 4; nt++) {
    ssum[nt] += __shfl_xor(ssum[nt], 16, 64);
    ssum[nt] += __shfl_xor(ssum[nt], 32, 64);
    ssq[nt] += __shfl_xor(ssq[nt], 16, 64);
    ssq[nt] += __shfl_xor(ssq[nt], 32, 64);
  }
  if (lane < 16) {
#pragma unroll
    for (int nt = 0; nt < 4; nt++) {
      psum[(size_t)waveId * 64 + nt * 16 + lane] = ssum[nt];
      psq[(size_t)waveId * 64 + nt * 16 + lane] = ssq[nt];
    }
  }
}

// ---- finalize BN: one block per channel ----
__global__ void bn_finalize(const float* __restrict__ psum, const float* __restrict__ psq,
                            const float* __restrict__ g, const float* __restrict__ b,
                            float* __restrict__ scale, float* __restrict__ shift,
                            float invN, int nw) {
  int c = blockIdx.x;
  float s = 0.f, q = 0.f;
  for (int i = threadIdx.x; i < nw; i += blockDim.x) {
    s += psum[(size_t)i * 64 + c];
    q += psq[(size_t)i * 64 + c];
  }
#pragma unroll
  for (int off = 32; off >= 1; off >>= 1) {
    s += __shfl_down(s, off, 64);
    q += __shfl_down(q, off, 64);
  }
  __shared__ float ls[4], lq[4];
  int wid = threadIdx.x >> 6;
  int lane = threadIdx.x & 63;
  if (lane == 0) { ls[wid] = s; lq[wid] = q; }
  __syncthreads();
  if (threadIdx.x == 0) {
    s = ls[0] + ls[1] + ls[2] + ls[3];
    q = lq[0] + lq[1] + lq[2] + lq[3];
    float mean = s * invN;
    float var = q * invN - mean * mean;
    float rstd = rsqrtf(var + EPSV);
    float sc = rstd * g[c];
    scale[c] = sc;
    shift[c] = b[c] - mean * sc;
  }
}

// ---- y = relu(h*scale + shift) (bf16 -> bf16) ----
__global__ void bn_relu_apply(const u16* __restrict__ h, const float* __restrict__ scale,
                              const float* __restrict__ shift, u16* __restrict__ y, int n8) {
  int i0 = blockIdx.x * blockDim.x + threadIdx.x;
  int c0 = (i0 * 8) & 63;
  float sc[8], sh[8];
#pragma unroll
  for (int j = 0; j < 8; j++) { sc[j] = scale[c0 + j]; sh[j] = shift[c0 + j]; }
  int stride = gridDim.x * blockDim.x;  // stride*8 multiple of 64 -> c0 invariant
  for (int i = i0; i < n8; i += stride) {
    u16x8 hv = reinterpret_cast<const u16x8*>(h)[i];
    u16x8 o;
#pragma unroll
    for (int j = 0; j < 8; j++) {
      float f = bf2f(hv[j]) * sc[j] + sh[j];
      o[j] = f2bf(fmaxf(f, 0.f));
    }
    reinterpret_cast<u16x8*>(y)[i] = o;
  }
}

// ---- out = relu(h*scale + shift + x) (f32 out) ----
__global__ void bn_add_relu(const u16* __restrict__ h, const float* __restrict__ scale,
                            const float* __restrict__ shift, const float* __restrict__ x,
                            float* __restrict__ out, int n8) {
  int i0 = blockIdx.x * blockDim.x + threadIdx.x;
  int c0 = (i0 * 8) & 63;
  float sc[8], sh[8];
#pragma unroll
  for (int j = 0; j < 8; j++) { sc[j] = scale[c0 + j]; sh[j] = shift[c0 + j]; }
  int stride = gridDim.x * blockDim.x;
  for (int i = i0; i < n8; i += stride) {
    u16x8 hv = reinterpret_cast<const u16x8*>(h)[i];
    const f32x4* xp = reinterpret_cast<const f32x4*>(x) + i * 2;
    f32x4 x0 = xp[0], x1 = xp[1];
    f32x4 o0, o1;
#pragma unroll
    for (int j = 0; j < 4; j++) {
      o0[j] = fmaxf(bf2f(hv[j]) * sc[j] + sh[j] + x0[j], 0.f);
      o1[j] = fmaxf(bf2f(hv[j + 4]) * sc[j + 4] + sh[j + 4] + x1[j], 0.f);
    }
    f32x4* op = reinterpret_cast<f32x4*>(out) + i * 2;
    op[0] = o0;
    op[1] = o1;
  }
}

extern "C" void kernel_launch(void* const* d_in, const int* in_sizes, int n_in,
                              void* d_out, int out_size, void* d_ws, size_t ws_size,
                              hipStream_t stream) {
  const float* x = (const float*)d_in[0];
  const int* nbr = (const int*)d_in[1];
  const int* msk = (const int*)d_in[2];
  const float* W1 = (const float*)d_in[3];
  const float* g1 = (const float*)d_in[4];
  const float* b1 = (const float*)d_in[5];
  const float* W2 = (const float*)d_in[6];
  const float* g2 = (const float*)d_in[7];
  const float* b2 = (const float*)d_in[8];
  float* out = (float*)d_out;

  const int N = in_sizes[0] / 64;     // 800000
  const int nquads = N / 64;          // 12500 waves, 1 quad (64 rows) each
  const int nblocks = nquads / 4;     // 3125 blocks of 4 waves (grid exact)
  const int n8 = N * 8;
  const size_t NC2 = (size_t)N * 64 * 2;      // one bf16 feature map
  const size_t MAPB = NC2 + 256;

  char* ws = (char*)d_ws;
  u16* bufA = (u16*)ws;                       // xg, then y1
  u16* bufB = (u16*)(ws + MAPB);              // h1, then h2
  u16* wf = (u16*)(ws + 2 * MAPB);            // 2 * 229376 B of B-fragments
  float* psum = (float*)(ws + 2 * MAPB + 512 * 1024);
  float* psq = psum + (size_t)nquads * 64;
  float* sc = psq + (size_t)nquads * 64;      // scale1|shift1|scale2|shift2

  // cidx_t ([N/16][28][16] ints, 89.6 MB) lives in d_out: dead until
  // bn_add_relu, which runs last and fully overwrites d_out.
  int* cidx_t = (int*)d_out;

  float invN = 1.0f / (float)N;

  prep_x<<<2048, 256, 0, stream>>>(x, bufA, n8);
  prep_tcidx<<<N / 128, 256, 0, stream>>>(nbr, msk, cidx_t);
  prep_w<<<112, 256, 0, stream>>>(W1, W2, wf);
  sconv<<<nblocks, 256, 0, stream>>>(bufA, cidx_t, wf, bufB, psum, psq);
  bn_finalize<<<64, 256, 0, stream>>>(psum, psq, g1, b1, sc, sc + 64, invN, nquads);
  bn_relu_apply<<<2048, 256, 0, stream>>>(bufB, sc, sc + 64, bufA, n8);
  sconv<<<nblocks, 256, 0, stream>>>(bufA, cidx_t, wf + FRAGS_PER_CONV * 8, bufB, psum, psq);
  bn_finalize<<<64, 256, 0, stream>>>(psum, psq, g2, b2, sc + 128, sc + 192, invN, nquads);
  bn_add_relu<<<2048, 256, 0, stream>>>(bufB, sc + 128, sc + 192, x, out, n8);
}